// Round 5
// baseline (26164.389 us; speedup 1.0000x reference)
//
#include <hip/hip_runtime.h>

#define B_  4096
#define T_  2048
#define H1_ 32
#define H2_ 16
#define RPB 4   // independent rows (1 per wave) per 256-thread block

#define LOG2E     1.44269504088896340736f
#define TWOLOG2E  2.88539008177792681472f

typedef float f32x2 __attribute__((ext_vector_type(2)));
typedef float f32x4 __attribute__((ext_vector_type(4)));

// packed fp32 fma via compiler (exact per-element fma -> v_pk_fma_f32)
#if defined(__has_builtin)
#if __has_builtin(__builtin_elementwise_fma)
#define PKFMA(acc, a, b) (acc) = __builtin_elementwise_fma((a), (b), (acc))
#endif
#endif
#ifndef PKFMA
#define PKFMA(acc, a, b) (acc) = (a) * (b) + (acc)  /* ffp-contract=fast fuses */
#endif

// exp2-domain activations (R2/R3-proven): weights/biases pre-scaled by log2e
// (sigmoid rows) or 2*log2e (tanh rows); sigmoid_core = rcp(1+exp2(-z)),
// tanh = fma(2, core, -1).
__device__ __forceinline__ float sig_core(float z) {
    return __builtin_amdgcn_rcpf(1.0f + __builtin_amdgcn_exp2f(-z));
}

__global__ __launch_bounds__(64 * RPB, 4) void lstm_deep_kernel(
    const float* __restrict__ x,
    const float* __restrict__ W_ih1,
    const float* __restrict__ W_hh1,
    const float* __restrict__ b_ih1,
    const float* __restrict__ b_hh1,
    const float* __restrict__ W_ih2,
    const float* __restrict__ W_hh2,
    const float* __restrict__ b_ih2,
    const float* __restrict__ b_hh2,
    const float* __restrict__ W_out,
    const float* __restrict__ b_out,
    float* __restrict__ out)
{
    const int tid  = threadIdx.x;
    const int lane = tid & 63;
    const int wid  = tid >> 6;                 // wave within block
    const int row  = blockIdx.x * RPB + wid;   // batch row (1 wave : 1 row)

    // per-wave private LDS slices; all conflicting accesses barrier-separated
    __shared__ __align__(16) float sh1[RPB][H1_];
    __shared__ __align__(16) float sh2[RPB][2][H2_];

    // ---- per-lane weights as f32x2 pairs (pre-scaled) ----
    const bool  low  = (lane < 32);
    const int   ga   = lane;        // layer1 rows: i (low) / f (high)
    const int   gb   = 64 + lane;   // layer1 rows: g (low, tanh) / o (high)
    const float scb1 = low ? TWOLOG2E : LOG2E;

    const f32x2* W1p = reinterpret_cast<const f32x2*>(W_hh1);   // rows of 16 pairs
    f32x2 w1a[H1_ / 2], w1b[H1_ / 2];
    #pragma unroll
    for (int j = 0; j < H1_ / 2; ++j) {
        w1a[j] = W1p[ga * (H1_ / 2) + j] * LOG2E;
        w1b[j] = W1p[gb * (H1_ / 2) + j] * scb1;
    }
    const float wxa = W_ih1[ga] * LOG2E;
    const float wxb = W_ih1[gb] * scb1;
    const float ba  = (b_ih1[ga] + b_hh1[ga]) * LOG2E;
    const float bb  = (b_ih1[gb] + b_hh1[gb]) * scb1;

    const int   gt  = lane >> 4;                 // layer2 gate: 0=i 1=f 2=g 3=o
    const float sc2 = (gt == 2) ? TWOLOG2E : LOG2E;
    const f32x2* W2ap = reinterpret_cast<const f32x2*>(W_ih2);  // rows of 16 pairs
    const f32x2* W2bp = reinterpret_cast<const f32x2*>(W_hh2);  // rows of 8 pairs
    f32x2 w2a[H1_ / 2];
    #pragma unroll
    for (int j = 0; j < H1_ / 2; ++j) w2a[j] = W2ap[lane * (H1_ / 2) + j] * sc2;
    f32x2 w2b[H2_ / 2];
    #pragma unroll
    for (int j = 0; j < H2_ / 2; ++j) w2b[j] = W2bp[lane * (H2_ / 2) + j] * sc2;
    const float b2 = (b_ih2[lane] + b_hh2[lane]) * sc2;

    // activation combine constants: act = fma(sc, sigmoid_core, of)
    const float sc1b = low ? 2.0f : 1.0f;
    const float of1b = low ? -1.0f : 0.0f;
    const float sc2c = (gt == 2) ? 2.0f : 1.0f;
    const float of2c = (gt == 2) ? -1.0f : 0.0f;

    const int   u2   = lane & 15;
    const float wout = W_out[u2];
    const float bout = b_out[0];

    // ---- state ----
    float c1 = 0.0f;   // valid in high lanes (unit lane-32)
    float c2 = 0.0f;   // replicated x4 (unit lane&15)
    if (lane < H1_) sh1[wid][lane] = 0.0f;
    if (lane < H2_) { sh2[wid][0][lane] = 0.0f; sh2[wid][1][lane] = 0.0f; }
    __syncthreads();

    const f32x4* __restrict__ xr4  = reinterpret_cast<const f32x4*>(x + (size_t)row * T_);
    float*       __restrict__ orow = out + (size_t)row * T_;

    auto step = [&](float xt, int par) -> float {
        // ---- layer 1: 2 gate rows/lane, packed chains over h1_{t-1} (LDS) ----
        f32x2 A  = {__builtin_fmaf(wxa, xt, ba), 0.0f};
        f32x2 Bv = {__builtin_fmaf(wxb, xt, bb), 0.0f};
        {
            const f32x4* p4 = reinterpret_cast<const f32x4*>(sh1[wid]);
            #pragma unroll
            for (int q = 0; q < H1_ / 4; ++q) {
                const f32x4 v = p4[q];
                const f32x2 h01 = {v.x, v.y};
                const f32x2 h23 = {v.z, v.w};
                PKFMA(A,  w1a[2 * q],     h01);
                PKFMA(Bv, w1b[2 * q],     h01);
                PKFMA(A,  w1a[2 * q + 1], h23);
                PKFMA(Bv, w1b[2 * q + 1], h23);
            }
        }
        const float acca = A.x + A.y;
        const float accb = Bv.x + Bv.y;

        const float sa = sig_core(acca);                             // sig(i) | sig(f)
        const float sb = __builtin_fmaf(sc1b, sig_core(accb), of1b); // tanh(g) | sig(o)
        const float pv = __shfl_xor(sa * sb, 32);   // high lanes get sig(i)*tanh(g)
        c1 = __builtin_fmaf(sa, c1, pv);            // high: sig(f)*c1 + p
        const float tc1 = __builtin_fmaf(2.0f, sig_core(TWOLOG2E * c1), -1.0f);
        const float h1new = sb * tc1;               // valid lanes 32..63

        if (lane >= 32) sh1[wid][lane - 32] = h1new;
        __syncthreads();   // R2-proven placement: write -> barrier -> re-reads

        // ---- layer 2: 1 gate row/lane, packed chains over [h1_t ; h2_{t-1}] ----
        f32x2 E = {b2, 0.0f};
        f32x2 F = {0.0f, 0.0f};
        {
            const f32x4* p4 = reinterpret_cast<const f32x4*>(sh1[wid]);
            #pragma unroll
            for (int q = 0; q < H1_ / 4; ++q) {
                const f32x4 v = p4[q];
                const f32x2 h01 = {v.x, v.y};
                const f32x2 h23 = {v.z, v.w};
                PKFMA(E, w2a[2 * q],     h01);
                PKFMA(F, w2a[2 * q + 1], h23);
            }
            const f32x4* q4 = reinterpret_cast<const f32x4*>(sh2[wid][par ^ 1]);
            #pragma unroll
            for (int q = 0; q < H2_ / 4; ++q) {
                const f32x4 v = q4[q];
                const f32x2 h01 = {v.x, v.y};
                const f32x2 h23 = {v.z, v.w};
                PKFMA(E, w2b[2 * q],     h01);
                PKFMA(F, w2b[2 * q + 1], h23);
            }
        }
        const float d2 = (E.x + E.y) + (F.x + F.y);

        const float s2 = __builtin_fmaf(sc2c, sig_core(d2), of2c);
        const float iv = __shfl(s2, u2);
        const float fv = __shfl(s2, u2 + 16);
        const float gv = __shfl(s2, u2 + 32);
        const float ov = __shfl(s2, u2 + 48);

        c2 = __builtin_fmaf(fv, c2, iv * gv);
        const float tc2 = __builtin_fmaf(2.0f, sig_core(TWOLOG2E * c2), -1.0f);
        const float h2v = ov * tc2;                 // h2_t[u2], replicated x4

        if (lane < H2_) sh2[wid][par][lane] = h2v;  // read next step, after its barrier

        // y = h2 . W_out + b_out (16-lane xor reduce)
        float part = wout * h2v;
        part += __shfl_xor(part, 1);
        part += __shfl_xor(part, 2);
        part += __shfl_xor(part, 4);
        part += __shfl_xor(part, 8);
        return part + bout;
    };

    f32x4 xv = xr4[0];
    #pragma unroll 1
    for (int t4 = 0; t4 < T_ / 4; ++t4) {
        const int nx = (t4 + 1 < T_ / 4) ? (t4 + 1) : t4;
        const f32x4 xn = xr4[nx];     // prefetch next 4 inputs

        const float y0 = step(xv.x, 0);
        const float y1 = step(xv.y, 1);
        const float y2 = step(xv.z, 0);
        const float y3 = step(xv.w, 1);

        if (lane == 0) {
            f32x4 yv = {y0, y1, y2, y3};
            *reinterpret_cast<f32x4*>(orow + 4 * t4) = yv;
        }
        xv = xn;
    }
}

extern "C" void kernel_launch(void* const* d_in, const int* in_sizes, int n_in,
                              void* d_out, int out_size, void* d_ws, size_t ws_size,
                              hipStream_t stream) {
    const float* xp     = (const float*)d_in[0];
    const float* W_ih1  = (const float*)d_in[1];
    const float* W_hh1  = (const float*)d_in[2];
    const float* b_ih1  = (const float*)d_in[3];
    const float* b_hh1  = (const float*)d_in[4];
    const float* W_ih2  = (const float*)d_in[5];
    const float* W_hh2  = (const float*)d_in[6];
    const float* b_ih2  = (const float*)d_in[7];
    const float* b_hh2  = (const float*)d_in[8];
    const float* W_out  = (const float*)d_in[9];
    const float* b_out  = (const float*)d_in[10];
    float* out = (float*)d_out;

    dim3 grid(B_ / RPB);
    dim3 block(64 * RPB);
    lstm_deep_kernel<<<grid, block, 0, stream>>>(
        xp, W_ih1, W_hh1, b_ih1, b_hh1, W_ih2, W_hh2, b_ih2, b_hh2, W_out, b_out, out);
}

// Round 6
// 2811.756 us; speedup vs baseline: 9.3054x; 9.3054x over previous
//
#include <hip/hip_runtime.h>

#define B_  4096
#define T_  2048
#define H1_ 32
#define H2_ 16
#define RPB 4   // independent rows (1 per wave) per 256-thread block

#define LOG2E     1.44269504088896340736f
#define TWOLOG2E  2.88539008177792681472f

typedef float f32x2 __attribute__((ext_vector_type(2)));
typedef float f32x4 __attribute__((ext_vector_type(4)));

// packed fp32 fma via compiler (exact per-element fma -> v_pk_fma_f32); R5-proven exact
#if defined(__has_builtin)
#if __has_builtin(__builtin_elementwise_fma)
#define PKFMA(acc, a, b) (acc) = __builtin_elementwise_fma((a), (b), (acc))
#endif
#endif
#ifndef PKFMA
#define PKFMA(acc, a, b) (acc) = (a) * (b) + (acc)  /* ffp-contract=fast fuses */
#endif

// exp2-domain activations (R2/R5-proven): weights/biases pre-scaled by log2e
// (sigmoid rows) or 2*log2e (tanh rows); sigmoid_core = rcp(1+exp2(-z)),
// tanh = fma(2, core, -1).
__device__ __forceinline__ float sig_core(float z) {
    return __builtin_amdgcn_rcpf(1.0f + __builtin_amdgcn_exp2f(-z));
}

__global__ __launch_bounds__(64 * RPB, 2) void lstm_deep_kernel(
    const float* __restrict__ x,
    const float* __restrict__ W_ih1,
    const float* __restrict__ W_hh1,
    const float* __restrict__ b_ih1,
    const float* __restrict__ b_hh1,
    const float* __restrict__ W_ih2,
    const float* __restrict__ W_hh2,
    const float* __restrict__ b_ih2,
    const float* __restrict__ b_hh2,
    const float* __restrict__ W_out,
    const float* __restrict__ b_out,
    float* __restrict__ out)
{
    const int tid  = threadIdx.x;
    const int lane = tid & 63;
    const int wid  = tid >> 6;                 // wave within block
    const int row  = blockIdx.x * RPB + wid;   // batch row (1 wave : 1 row)

    // ---- LDS: staged weights (block-shared) + per-wave h slices ----
    __shared__ __align__(16) float W1s[4 * H1_ * H1_];    // W_hh1: 4096 f, 16 KB
    __shared__ __align__(16) float W2as[4 * H2_ * H1_];   // W_ih2: 2048 f,  8 KB
    __shared__ __align__(16) float W2bs[4 * H2_ * H2_];   // W_hh2: 1024 f,  4 KB
    __shared__ __align__(16) float sh1[RPB][H1_];
    __shared__ __align__(16) float sh2[RPB][2][H2_];

    // cooperative global->LDS staging (coalesced float4), one-time
    {
        const f32x4* g1 = reinterpret_cast<const f32x4*>(W_hh1);
        f32x4*       s1 = reinterpret_cast<f32x4*>(W1s);
        #pragma unroll
        for (int i = 0; i < 4; ++i) s1[tid + 256 * i] = g1[tid + 256 * i];   // 1024 vec4
        const f32x4* g2 = reinterpret_cast<const f32x4*>(W_ih2);
        f32x4*       s2 = reinterpret_cast<f32x4*>(W2as);
        #pragma unroll
        for (int i = 0; i < 2; ++i) s2[tid + 256 * i] = g2[tid + 256 * i];   // 512 vec4
        const f32x4* g3 = reinterpret_cast<const f32x4*>(W_hh2);
        f32x4*       s3 = reinterpret_cast<f32x4*>(W2bs);
        if (tid < 256) s3[tid] = g3[tid];                                    // 256 vec4
    }
    if (lane < H1_) sh1[wid][lane] = 0.0f;
    if (lane < H2_) { sh2[wid][0][lane] = 0.0f; sh2[wid][1][lane] = 0.0f; }
    __syncthreads();

    // ---- per-lane weights LDS->VGPR (non-rematerializable), pre-scaled ----
    const bool  low  = (lane < 32);
    const int   ga   = lane;        // layer1 rows: i (low) / f (high)
    const int   gb   = 64 + lane;   // layer1 rows: g (low, tanh) / o (high)
    const float scb1 = low ? TWOLOG2E : LOG2E;

    const f32x2* W1p = reinterpret_cast<const f32x2*>(W1s);
    f32x2 w1a[H1_ / 2], w1b[H1_ / 2];
    #pragma unroll
    for (int j = 0; j < H1_ / 2; ++j) {
        w1a[j] = W1p[ga * (H1_ / 2) + j] * LOG2E;
        w1b[j] = W1p[gb * (H1_ / 2) + j] * scb1;
    }
    const int   gt  = lane >> 4;                 // layer2 gate: 0=i 1=f 2=g 3=o
    const float sc2 = (gt == 2) ? TWOLOG2E : LOG2E;
    const f32x2* W2ap = reinterpret_cast<const f32x2*>(W2as);
    const f32x2* W2bp = reinterpret_cast<const f32x2*>(W2bs);
    f32x2 w2a[H1_ / 2];
    #pragma unroll
    for (int j = 0; j < H1_ / 2; ++j) w2a[j] = W2ap[lane * (H1_ / 2) + j] * sc2;
    f32x2 w2b[H2_ / 2];
    #pragma unroll
    for (int j = 0; j < H2_ / 2; ++j) w2b[j] = W2bp[lane * (H2_ / 2) + j] * sc2;

    // biases / small vectors straight from global (few regs, cheap either way)
    const float wxa = W_ih1[ga] * LOG2E;
    const float wxb = W_ih1[gb] * scb1;
    const float ba  = (b_ih1[ga] + b_hh1[ga]) * LOG2E;
    const float bb  = (b_ih1[gb] + b_hh1[gb]) * scb1;
    const float b2  = (b_ih2[lane] + b_hh2[lane]) * sc2;

    // activation combine constants: act = fma(sc, sigmoid_core, of)
    const float sc1b = low ? 2.0f : 1.0f;
    const float of1b = low ? -1.0f : 0.0f;
    const float sc2c = (gt == 2) ? 2.0f : 1.0f;
    const float of2c = (gt == 2) ? -1.0f : 0.0f;

    const int   u2   = lane & 15;
    const float wout = W_out[u2];
    const float bout = b_out[0];

    // ---- state ----
    float c1 = 0.0f;   // valid in high lanes (unit lane-32)
    float c2 = 0.0f;   // replicated x4 (unit lane&15)

    const f32x4* __restrict__ xr4  = reinterpret_cast<const f32x4*>(x + (size_t)row * T_);
    float*       __restrict__ orow = out + (size_t)row * T_;

    auto step = [&](float xt, int par) -> float {
        // ---- layer 1: 2 gate rows/lane, packed chains over h1_{t-1} (LDS bcast) ----
        f32x2 A  = {__builtin_fmaf(wxa, xt, ba), 0.0f};
        f32x2 Bv = {__builtin_fmaf(wxb, xt, bb), 0.0f};
        {
            const f32x4* p4 = reinterpret_cast<const f32x4*>(sh1[wid]);
            #pragma unroll
            for (int q = 0; q < H1_ / 4; ++q) {
                const f32x4 v = p4[q];
                const f32x2 h01 = {v.x, v.y};
                const f32x2 h23 = {v.z, v.w};
                PKFMA(A,  w1a[2 * q],     h01);
                PKFMA(Bv, w1b[2 * q],     h01);
                PKFMA(A,  w1a[2 * q + 1], h23);
                PKFMA(Bv, w1b[2 * q + 1], h23);
            }
        }
        const float acca = A.x + A.y;
        const float accb = Bv.x + Bv.y;

        const float sa = sig_core(acca);                             // sig(i) | sig(f)
        const float sb = __builtin_fmaf(sc1b, sig_core(accb), of1b); // tanh(g) | sig(o)
        const float pv = __shfl_xor(sa * sb, 32);   // high lanes get sig(i)*tanh(g)
        c1 = __builtin_fmaf(sa, c1, pv);            // high: sig(f)*c1 + p
        const float tc1 = __builtin_fmaf(2.0f, sig_core(TWOLOG2E * c1), -1.0f);
        const float h1new = sb * tc1;               // valid lanes 32..63

        if (lane >= 32) sh1[wid][lane - 32] = h1new;
        __syncthreads();   // proven placement: write -> barrier -> re-reads

        // ---- layer 2: 1 gate row/lane, packed chains over [h1_t ; h2_{t-1}] ----
        f32x2 E = {b2, 0.0f};
        f32x2 F = {0.0f, 0.0f};
        {
            const f32x4* p4 = reinterpret_cast<const f32x4*>(sh1[wid]);
            #pragma unroll
            for (int q = 0; q < H1_ / 4; ++q) {
                const f32x4 v = p4[q];
                const f32x2 h01 = {v.x, v.y};
                const f32x2 h23 = {v.z, v.w};
                PKFMA(E, w2a[2 * q],     h01);
                PKFMA(F, w2a[2 * q + 1], h23);
            }
            const f32x4* q4 = reinterpret_cast<const f32x4*>(sh2[wid][par ^ 1]);
            #pragma unroll
            for (int q = 0; q < H2_ / 4; ++q) {
                const f32x4 v = q4[q];
                const f32x2 h01 = {v.x, v.y};
                const f32x2 h23 = {v.z, v.w};
                PKFMA(E, w2b[2 * q],     h01);
                PKFMA(F, w2b[2 * q + 1], h23);
            }
        }
        const float d2 = (E.x + E.y) + (F.x + F.y);

        const float s2 = __builtin_fmaf(sc2c, sig_core(d2), of2c);
        const float iv = __shfl(s2, u2);
        const float fv = __shfl(s2, u2 + 16);
        const float gv = __shfl(s2, u2 + 32);
        const float ov = __shfl(s2, u2 + 48);

        c2 = __builtin_fmaf(fv, c2, iv * gv);
        const float tc2 = __builtin_fmaf(2.0f, sig_core(TWOLOG2E * c2), -1.0f);
        const float h2v = ov * tc2;                 // h2_t[u2], replicated x4

        if (lane < H2_) sh2[wid][par][lane] = h2v;  // read next step, after its barrier

        // y = h2 . W_out + b_out (16-lane xor reduce)
        float part = wout * h2v;
        part += __shfl_xor(part, 1);
        part += __shfl_xor(part, 2);
        part += __shfl_xor(part, 4);
        part += __shfl_xor(part, 8);
        return part + bout;
    };

    f32x4 xv = xr4[0];
    #pragma unroll 1
    for (int t4 = 0; t4 < T_ / 4; ++t4) {
        const int nx = (t4 + 1 < T_ / 4) ? (t4 + 1) : t4;
        const f32x4 xn = xr4[nx];     // prefetch next 4 inputs

        const float y0 = step(xv.x, 0);
        const float y1 = step(xv.y, 1);
        const float y2 = step(xv.z, 0);
        const float y3 = step(xv.w, 1);

        if (lane == 0) {
            f32x4 yv = {y0, y1, y2, y3};
            *reinterpret_cast<f32x4*>(orow + 4 * t4) = yv;
        }
        xv = xn;
    }
}

extern "C" void kernel_launch(void* const* d_in, const int* in_sizes, int n_in,
                              void* d_out, int out_size, void* d_ws, size_t ws_size,
                              hipStream_t stream) {
    const float* xp     = (const float*)d_in[0];
    const float* W_ih1  = (const float*)d_in[1];
    const float* W_hh1  = (const float*)d_in[2];
    const float* b_ih1  = (const float*)d_in[3];
    const float* b_hh1  = (const float*)d_in[4];
    const float* W_ih2  = (const float*)d_in[5];
    const float* W_hh2  = (const float*)d_in[6];
    const float* b_ih2  = (const float*)d_in[7];
    const float* b_hh2  = (const float*)d_in[8];
    const float* W_out  = (const float*)d_in[9];
    const float* b_out  = (const float*)d_in[10];
    float* out = (float*)d_out;

    dim3 grid(B_ / RPB);
    dim3 block(64 * RPB);
    lstm_deep_kernel<<<grid, block, 0, stream>>>(
        xp, W_ih1, W_hh1, b_ih1, b_hh1, W_ih2, W_hh2, b_ih2, b_hh2, W_out, b_out, out);
}